// Round 2
// baseline (7253.068 us; speedup 1.0000x reference)
//
#include <hip/hip_runtime.h>
#include <math.h>

// ---------------- sizes ----------------
// x: [32,3,128,128]; enc: 64^2 then 32^2 @256ch; K=512 codes, D=256.
// d_out = [x_tilde (32*3*128*128)] [z_e_x (32*256*32*32)] [z_q_x (same)]

// e2[k] = sum_d emb[k][d]^2
__global__ void k_e2(const float* __restrict__ emb, float* __restrict__ e2) {
    int k = blockIdx.x * 256 + threadIdx.x;
    if (k < 512) {
        const float* r = emb + k * 256;
        float s = 0.f;
        #pragma unroll 8
        for (int d = 0; d < 256; ++d) s += r[d] * r[d];
        e2[k] = s;
    }
}

// conv 4x4 s2 p1, Cin=3, 128->64, +bias, ReLU.  block (64,4), grid (16,256,32)
__global__ __launch_bounds__(256) void k_conv1(const float* __restrict__ in,
        const float* __restrict__ w, const float* __restrict__ bias,
        float* __restrict__ out) {
    int x = threadIdx.x;
    int y = blockIdx.x * 4 + threadIdx.y;
    int co = blockIdx.y, b = blockIdx.z;
    const float* wc = w + co * 48;
    float acc = bias[co];
    #pragma unroll
    for (int ci = 0; ci < 3; ++ci) {
        const float* ip = in + ((b * 3 + ci) * 128) * 128;
        #pragma unroll
        for (int ky = 0; ky < 4; ++ky) {
            int iy = 2 * y - 1 + ky;
            if ((unsigned)iy < 128u) {
                #pragma unroll
                for (int kx = 0; kx < 4; ++kx) {
                    int ix = 2 * x - 1 + kx;
                    if ((unsigned)ix < 128u)
                        acc = fmaf(wc[(ci * 4 + ky) * 4 + kx], ip[iy * 128 + ix], acc);
                }
            }
        }
    }
    out[((b * 256 + co) * 64 + y) * 64 + x] = fmaxf(acc, 0.f);
}

// conv 4x4 s2 p1, Cin=Cout=256, 64->32, +bias, ReLU.
// block 256, grid (co_blk=32, b=32). thread: 2x2 outputs x 8 co.
__global__ __launch_bounds__(256) void k_conv2(const float* __restrict__ in,
        const float* __restrict__ w, const float* __restrict__ bias,
        float* __restrict__ out) {
    __shared__ float tile[66 * 68];
    __shared__ float wl[128];
    int t = threadIdx.x;
    int co0 = blockIdx.x * 8, b = blockIdx.y;
    for (int i = t; i < 66 * 68; i += 256) tile[i] = 0.f;
    int qy = t >> 4, qx = t & 15;
    float acc[8][2][2];
    #pragma unroll
    for (int c = 0; c < 8; ++c)
        #pragma unroll
        for (int dy = 0; dy < 2; ++dy)
            #pragma unroll
            for (int dx = 0; dx < 2; ++dx) acc[c][dy][dx] = 0.f;
    for (int ci = 0; ci < 256; ++ci) {
        __syncthreads();
        const float* ip = in + ((b * 256 + ci) * 64) * 64;
        #pragma unroll
        for (int i = 0; i < 16; ++i) {
            int l = i * 256 + t;                  // 0..4095
            tile[((l >> 6) + 1) * 68 + (l & 63) + 1] = ip[l];
        }
        if (t < 128) wl[t] = w[(co0 + (t >> 4)) * 4096 + ci * 16 + (t & 15)];
        __syncthreads();
        float v[6][6];
        #pragma unroll
        for (int r = 0; r < 6; ++r)
            #pragma unroll
            for (int c2 = 0; c2 < 6; ++c2)
                v[r][c2] = tile[(4 * qy + r) * 68 + 4 * qx + c2];
        #pragma unroll
        for (int c = 0; c < 8; ++c) {
            float wr[16];
            #pragma unroll
            for (int k = 0; k < 16; ++k) wr[k] = wl[c * 16 + k];
            #pragma unroll
            for (int dy = 0; dy < 2; ++dy)
                #pragma unroll
                for (int dx = 0; dx < 2; ++dx)
                    #pragma unroll
                    for (int ky = 0; ky < 4; ++ky)
                        #pragma unroll
                        for (int kx = 0; kx < 4; ++kx)
                            acc[c][dy][dx] = fmaf(wr[ky * 4 + kx],
                                v[2 * dy + ky][2 * dx + kx], acc[c][dy][dx]);
        }
    }
    #pragma unroll
    for (int c = 0; c < 8; ++c) {
        float bb = bias[co0 + c];
        #pragma unroll
        for (int dy = 0; dy < 2; ++dy)
            #pragma unroll
            for (int dx = 0; dx < 2; ++dx)
                out[((b * 256 + co0 + c) * 32 + 2 * qy + dy) * 32 + 2 * qx + dx] =
                    fmaxf(acc[c][dy][dx] + bb, 0.f);
    }
}

// conv 3x3 p1 @32x32, Cin=Cout=256, input pre-ReLU, out = conv + bias (raw).
// block 256, grid (co_blk=16, b=32). thread: 2x2 outputs x 16 co.
__global__ __launch_bounds__(256) void k_conv3x3(const float* __restrict__ in,
        const float* __restrict__ w, const float* __restrict__ bias,
        float* __restrict__ out) {
    __shared__ float tile[34 * 36];
    __shared__ float wl[144];
    int t = threadIdx.x;
    int co0 = blockIdx.x * 16, b = blockIdx.y;
    for (int i = t; i < 34 * 36; i += 256) tile[i] = 0.f;
    int qy = t >> 4, qx = t & 15;
    int wc = t / 9, wk = t % 9;  // weight-stage mapping (t<144)
    float acc[16][2][2];
    #pragma unroll
    for (int c = 0; c < 16; ++c)
        #pragma unroll
        for (int dy = 0; dy < 2; ++dy)
            #pragma unroll
            for (int dx = 0; dx < 2; ++dx) acc[c][dy][dx] = 0.f;
    for (int ci = 0; ci < 256; ++ci) {
        __syncthreads();
        const float* ip = in + (b * 256 + ci) * 1024;
        #pragma unroll
        for (int i = 0; i < 4; ++i) {
            int l = i * 256 + t;
            float v = fmaxf(ip[l], 0.f);          // pre-ReLU
            tile[((l >> 5) + 1) * 36 + (l & 31) + 1] = v;
        }
        if (t < 144) wl[t] = w[(co0 + wc) * 2304 + ci * 9 + wk];
        __syncthreads();
        float v[5][5];
        #pragma unroll
        for (int r = 0; r < 5; ++r)
            #pragma unroll
            for (int c2 = 0; c2 < 5; ++c2)
                v[r][c2] = tile[(2 * qy + r) * 36 + 2 * qx + c2];
        #pragma unroll
        for (int c = 0; c < 16; ++c) {
            float wr[9];
            #pragma unroll
            for (int k = 0; k < 9; ++k) wr[k] = wl[c * 9 + k];
            #pragma unroll
            for (int dy = 0; dy < 2; ++dy)
                #pragma unroll
                for (int dx = 0; dx < 2; ++dx)
                    #pragma unroll
                    for (int ky = 0; ky < 3; ++ky)
                        #pragma unroll
                        for (int kx = 0; kx < 3; ++kx)
                            acc[c][dy][dx] = fmaf(wr[ky * 3 + kx],
                                v[dy + ky][dx + kx], acc[c][dy][dx]);
        }
    }
    #pragma unroll
    for (int c = 0; c < 16; ++c) {
        float bb = bias[co0 + c];
        #pragma unroll
        for (int dy = 0; dy < 2; ++dy)
            #pragma unroll
            for (int dx = 0; dx < 2; ++dx)
                out[((b * 256 + co0 + c) * 32 + 2 * qy + dy) * 32 + 2 * qx + dx] =
                    acc[c][dy][dx] + bb;
    }
}

// out = skip + bias + sum_ci w[co,ci] * relu(tin[ci])   @32x32
// block 256, grid (co_blk=32, b=32). thread: 4 spatial x 8 co.
__global__ __launch_bounds__(256) void k_res1x1(const float* __restrict__ tin,
        const float* __restrict__ skip, const float* __restrict__ w,
        const float* __restrict__ bias, float* __restrict__ out) {
    __shared__ float tl[1024];
    int t = threadIdx.x;
    int co0 = blockIdx.x * 8, b = blockIdx.y;
    float acc[8][4];
    #pragma unroll
    for (int c = 0; c < 8; ++c)
        #pragma unroll
        for (int j = 0; j < 4; ++j) acc[c][j] = 0.f;
    for (int ci = 0; ci < 256; ++ci) {
        __syncthreads();
        const float* ip = tin + (b * 256 + ci) * 1024;
        #pragma unroll
        for (int j = 0; j < 4; ++j) tl[j * 256 + t] = fmaxf(ip[j * 256 + t], 0.f);
        __syncthreads();
        float v[4];
        #pragma unroll
        for (int j = 0; j < 4; ++j) v[j] = tl[j * 256 + t];
        #pragma unroll
        for (int c = 0; c < 8; ++c) {
            float wv = w[(co0 + c) * 256 + ci];   // uniform -> scalar load
            #pragma unroll
            for (int j = 0; j < 4; ++j) acc[c][j] = fmaf(wv, v[j], acc[c][j]);
        }
    }
    #pragma unroll
    for (int c = 0; c < 8; ++c) {
        float bb = bias[co0 + c];
        const float* sp = skip + (b * 256 + co0 + c) * 1024;
        float* op = out + (b * 256 + co0 + c) * 1024;
        #pragma unroll
        for (int j = 0; j < 4; ++j)
            op[j * 256 + t] = sp[j * 256 + t] + bb + acc[c][j];
    }
}

// VQ: lat[b,y,x] = argmin_k ( e2[k] - 2 * dot(z[b,:,y,x], emb[k]) )
// block 256, grid (y=32, b=32). thread: 4 pos x 8 k, 2 passes over k.
__global__ __launch_bounds__(256) void k_vq(const float* __restrict__ ze,
        const float* __restrict__ emb, const float* __restrict__ e2,
        int* __restrict__ lat) {
    __shared__ __align__(16) float zt[256 * 36];   // zt[d][pos], row stride 36
    __shared__ float sv[256 * 4];
    __shared__ int   si[256 * 4];
    int t = threadIdx.x;
    int y = blockIdx.x, b = blockIdx.y;
    const float* zp = ze + (b * 256) * 1024 + y * 32;  // + d*1024 + x
    #pragma unroll
    for (int i = 0; i < 32; ++i) {
        int l = i * 256 + t;
        zt[(l >> 5) * 36 + (l & 31)] = zp[(l >> 5) * 1024 + (l & 31)];
    }
    __syncthreads();
    int g = t & 7;        // pos group: pos = 4g..4g+3
    int kg = t >> 3;      // 0..31
    float minv[4] = {1e30f, 1e30f, 1e30f, 1e30f};
    int   mink[4] = {0, 0, 0, 0};
    for (int pass = 0; pass < 2; ++pass) {
        float acc[4][8];
        #pragma unroll
        for (int p = 0; p < 4; ++p)
            #pragma unroll
            for (int j = 0; j < 8; ++j) acc[p][j] = 0.f;
        int k0 = pass * 256 + kg * 8;
        const float* ep = emb + k0 * 256;
        for (int d = 0; d < 256; ++d) {
            const float4 zv = *(const float4*)&zt[d * 36 + 4 * g];
            #pragma unroll
            for (int j = 0; j < 8; ++j) {
                float ev = ep[j * 256 + d];
                acc[0][j] = fmaf(ev, zv.x, acc[0][j]);
                acc[1][j] = fmaf(ev, zv.y, acc[1][j]);
                acc[2][j] = fmaf(ev, zv.z, acc[2][j]);
                acc[3][j] = fmaf(ev, zv.w, acc[3][j]);
            }
        }
        #pragma unroll
        for (int j = 0; j < 8; ++j) {
            int k = k0 + j;
            float ee = e2[k];
            #pragma unroll
            for (int p = 0; p < 4; ++p) {
                float dist = ee - 2.f * acc[p][j];
                if (dist < minv[p]) { minv[p] = dist; mink[p] = k; }
            }
        }
    }
    #pragma unroll
    for (int p = 0; p < 4; ++p) { sv[t * 4 + p] = minv[p]; si[t * 4 + p] = mink[p]; }
    __syncthreads();
    if (t < 32) {
        int gg = t >> 2, s = t & 3;
        float bv = 1e30f; int bk = 0x7fffffff;
        for (int m = 0; m < 32; ++m) {
            int tt = gg + 8 * m;
            float v = sv[tt * 4 + s]; int k = si[tt * 4 + s];
            if (v < bv || (v == bv && k < bk)) { bv = v; bk = k; }
        }
        lat[(b * 32 + y) * 32 + t] = bk;
    }
}

// z_q gather: zq[b,d,y,x] = emb[lat[b,y,x]][d].  block 256, grid (y=32,b=32)
__global__ __launch_bounds__(256) void k_gather(const int* __restrict__ lat,
        const float* __restrict__ emb, float* __restrict__ zq) {
    __shared__ int ll[32];
    int t = threadIdx.x, y = blockIdx.x, b = blockIdx.y;
    if (t < 32) ll[t] = lat[(b * 32 + y) * 32 + t];
    __syncthreads();
    #pragma unroll
    for (int i = 0; i < 32; ++i) {
        int l = i * 256 + t;
        int d = l >> 5, x = l & 31;
        zq[(b * 256 + d) * 1024 + y * 32 + x] = emb[ll[x] * 256 + d];
    }
}

// convT 4x4 s2 p1, 256->256, 32->64, +bias, ReLU.  w layout [ci][co][ky][kx]
// block 256, grid (co_pair=128, b=32). thread: 4x4 outputs x 2 co.
__global__ __launch_bounds__(256) void k_convt1(const float* __restrict__ in,
        const float* __restrict__ w, const float* __restrict__ bias,
        float* __restrict__ out) {
    __shared__ float tile[34 * 36];
    __shared__ float wl[32];
    int t = threadIdx.x;
    int co0 = blockIdx.x * 2, b = blockIdx.y;
    for (int i = t; i < 34 * 36; i += 256) tile[i] = 0.f;
    int qy = t >> 4, qx = t & 15;
    float acc[2][4][4];
    #pragma unroll
    for (int c = 0; c < 2; ++c)
        #pragma unroll
        for (int dy = 0; dy < 4; ++dy)
            #pragma unroll
            for (int dx = 0; dx < 4; ++dx) acc[c][dy][dx] = 0.f;
    for (int ci = 0; ci < 256; ++ci) {
        __syncthreads();
        const float* ip = in + (b * 256 + ci) * 1024;
        #pragma unroll
        for (int i = 0; i < 4; ++i) {
            int l = i * 256 + t;
            tile[((l >> 5) + 1) * 36 + (l & 31) + 1] = ip[l];
        }
        if (t < 32) wl[t] = w[ci * 4096 + (co0 + (t >> 4)) * 16 + (t & 15)];
        __syncthreads();
        float v[4][4];
        #pragma unroll
        for (int r = 0; r < 4; ++r)
            #pragma unroll
            for (int s = 0; s < 4; ++s)
                v[r][s] = tile[(2 * qy + r) * 36 + 2 * qx + s];
        #pragma unroll
        for (int c = 0; c < 2; ++c) {
            float wr[16];
            #pragma unroll
            for (int k = 0; k < 16; ++k) wr[k] = wl[c * 16 + k];
            #pragma unroll
            for (int dy = 0; dy < 4; ++dy)
                #pragma unroll
                for (int ky = 0; ky < 4; ++ky)
                    if (((dy + 1 - ky) & 1) == 0) {
                        const int r = (dy + 1 - ky) / 2 + 1;
                        #pragma unroll
                        for (int dx = 0; dx < 4; ++dx)
                            #pragma unroll
                            for (int kx = 0; kx < 4; ++kx)
                                if (((dx + 1 - kx) & 1) == 0) {
                                    const int s = (dx + 1 - kx) / 2 + 1;
                                    acc[c][dy][dx] = fmaf(wr[ky * 4 + kx], v[r][s],
                                                          acc[c][dy][dx]);
                                }
                    }
        }
    }
    #pragma unroll
    for (int c = 0; c < 2; ++c) {
        float bb = bias[co0 + c];
        #pragma unroll
        for (int dy = 0; dy < 4; ++dy)
            #pragma unroll
            for (int dx = 0; dx < 4; ++dx)
                out[((b * 256 + co0 + c) * 64 + 4 * qy + dy) * 64 + 4 * qx + dx] =
                    fmaxf(acc[c][dy][dx] + bb, 0.f);
    }
}

// convT 4x4 s2 p1, 256->3, 64->128, +bias, sigmoid.  w layout [ci][co][ky][kx]
// block 256, grid (ytile=8, co=3, b=32). thread: 2x4 outputs.
__global__ __launch_bounds__(256) void k_convt2(const float* __restrict__ in,
        const float* __restrict__ w, const float* __restrict__ bias,
        float* __restrict__ out) {
    __shared__ float tile[10 * 68];
    __shared__ float wl[16];
    int t = threadIdx.x;
    int y0 = blockIdx.x * 16, co = blockIdx.y, b = blockIdx.z;
    int qy = t >> 5, qx = t & 31;
    float acc[2][4];
    #pragma unroll
    for (int dy = 0; dy < 2; ++dy)
        #pragma unroll
        for (int dx = 0; dx < 4; ++dx) acc[dy][dx] = 0.f;
    int iy0 = y0 / 2 - 1;
    for (int ci = 0; ci < 256; ++ci) {
        __syncthreads();
        const float* ip = in + (b * 256 + ci) * 4096;
        for (int l = t; l < 660; l += 256) {
            int r = l / 66, c2 = l % 66;
            int iy = iy0 + r, ix = c2 - 1;
            float v = 0.f;
            if ((unsigned)iy < 64u && (unsigned)ix < 64u) v = ip[iy * 64 + ix];
            tile[r * 68 + c2] = v;
        }
        if (t < 16) wl[t] = w[ci * 48 + co * 16 + t];
        __syncthreads();
        float v[3][4];
        #pragma unroll
        for (int r = 0; r < 3; ++r)
            #pragma unroll
            for (int s = 0; s < 4; ++s)
                v[r][s] = tile[(qy + r) * 68 + 2 * qx + s];
        float wr[16];
        #pragma unroll
        for (int k = 0; k < 16; ++k) wr[k] = wl[k];
        #pragma unroll
        for (int dy = 0; dy < 2; ++dy)
            #pragma unroll
            for (int ky = 0; ky < 4; ++ky)
                if (((dy + 1 - ky) & 1) == 0) {
                    const int r = (dy + 1 - ky) / 2 + 1;
                    #pragma unroll
                    for (int dx = 0; dx < 4; ++dx)
                        #pragma unroll
                        for (int kx = 0; kx < 4; ++kx)
                            if (((dx + 1 - kx) & 1) == 0) {
                                const int s = (dx + 1 - kx) / 2 + 1;
                                acc[dy][dx] = fmaf(wr[ky * 4 + kx], v[r][s], acc[dy][dx]);
                            }
                }
    }
    float bb = bias[co];
    #pragma unroll
    for (int dy = 0; dy < 2; ++dy)
        #pragma unroll
        for (int dx = 0; dx < 4; ++dx) {
            int oy = y0 + 2 * qy + dy, ox = 4 * qx + dx;
            float vv = acc[dy][dx] + bb;
            out[(b * 3 + co) * 16384 + oy * 128 + ox] = 1.f / (1.f + __expf(-vv));
        }
}

extern "C" void kernel_launch(void* const* d_in, const int* in_sizes, int n_in,
                              void* d_out, int out_size, void* d_ws, size_t ws_size,
                              hipStream_t stream) {
    const float* x     = (const float*)d_in[0];
    const float* ec1w  = (const float*)d_in[1];
    const float* ec1b  = (const float*)d_in[2];
    const float* ec2w  = (const float*)d_in[3];
    const float* ec2b  = (const float*)d_in[4];
    const float* er1w1 = (const float*)d_in[5];
    const float* er1b1 = (const float*)d_in[6];
    const float* er1w2 = (const float*)d_in[7];
    const float* er1b2 = (const float*)d_in[8];
    const float* er2w1 = (const float*)d_in[9];
    const float* er2b1 = (const float*)d_in[10];
    const float* er2w2 = (const float*)d_in[11];
    const float* er2b2 = (const float*)d_in[12];
    const float* emb   = (const float*)d_in[13];
    const float* dr1w1 = (const float*)d_in[14];
    const float* dr1b1 = (const float*)d_in[15];
    const float* dr1w2 = (const float*)d_in[16];
    const float* dr1b2 = (const float*)d_in[17];
    const float* dr2w1 = (const float*)d_in[18];
    const float* dr2b1 = (const float*)d_in[19];
    const float* dr2w2 = (const float*)d_in[20];
    const float* dr2b2 = (const float*)d_in[21];
    const float* dt1w  = (const float*)d_in[22];
    const float* dt1b  = (const float*)d_in[23];
    const float* dt2w  = (const float*)d_in[24];
    const float* dt2b  = (const float*)d_in[25];

    float* outp = (float*)d_out;
    float* xt = outp;                          // 1,572,864
    float* ze = outp + 1572864;                // 8,388,608
    float* zq = ze + 8388608;                  // 8,388,608

    float* buf1 = (float*)d_ws;                // 33,554,432 (64^2 x 256)
    float* buf2 = buf1 + 33554432;             // 8,388,608  (32^2 x 256)
    float* buf3 = buf2 + 8388608;
    float* buf4 = buf3 + 8388608;
    float* e2v  = buf4 + 8388608;              // 512
    int*   lat  = (int*)(e2v + 512);           // 32768

    k_e2<<<2, 256, 0, stream>>>(emb, e2v);
    // encoder
    k_conv1<<<dim3(16, 256, 32), dim3(64, 4), 0, stream>>>(x, ec1w, ec1b, buf1);
    k_conv2<<<dim3(32, 32), 256, 0, stream>>>(buf1, ec2w, ec2b, buf2);
    k_conv3x3<<<dim3(16, 32), 256, 0, stream>>>(buf2, er1w1, er1b1, buf3);
    k_res1x1<<<dim3(32, 32), 256, 0, stream>>>(buf3, buf2, er1w2, er1b2, buf4);
    k_conv3x3<<<dim3(16, 32), 256, 0, stream>>>(buf4, er2w1, er2b1, buf3);
    k_res1x1<<<dim3(32, 32), 256, 0, stream>>>(buf3, buf4, er2w2, er2b2, ze);
    // VQ
    k_vq<<<dim3(32, 32), 256, 0, stream>>>(ze, emb, e2v, lat);
    k_gather<<<dim3(32, 32), 256, 0, stream>>>(lat, emb, zq);
    // decoder
    k_conv3x3<<<dim3(16, 32), 256, 0, stream>>>(zq, dr1w1, dr1b1, buf3);
    k_res1x1<<<dim3(32, 32), 256, 0, stream>>>(buf3, zq, dr1w2, dr1b2, buf4);
    k_conv3x3<<<dim3(16, 32), 256, 0, stream>>>(buf4, dr2w1, dr2b1, buf3);
    k_res1x1<<<dim3(32, 32), 256, 0, stream>>>(buf3, buf4, dr2w2, dr2b2, buf2);
    k_convt1<<<dim3(128, 32), 256, 0, stream>>>(buf2, dt1w, dt1b, buf1);
    k_convt2<<<dim3(8, 3, 32), 256, 0, stream>>>(buf1, dt2w, dt2b, xt);
}

// Round 3
// 1661.078 us; speedup vs baseline: 4.3665x; 4.3665x over previous
//
#include <hip/hip_runtime.h>
#include <math.h>

typedef unsigned short ushort_t;
using frag_ab = __attribute__((ext_vector_type(8))) short;
using f32x4   = __attribute__((ext_vector_type(4))) float;

__device__ __forceinline__ float b2f(unsigned short u) {
    return __uint_as_float(((unsigned)u) << 16);
}
__device__ __forceinline__ unsigned short f2b(float f) {
    unsigned u = __float_as_uint(f);
    u += 0x7fffu + ((u >> 16) & 1u);       // RNE
    return (unsigned short)(u >> 16);
}
__device__ __forceinline__ void bf8_to_f(uint4 v, float* f) {
    const unsigned* p = (const unsigned*)&v;
    #pragma unroll
    for (int q = 0; q < 4; ++q) {
        unsigned u = p[q];
        f[2*q]   = __uint_as_float(u << 16);
        f[2*q+1] = __uint_as_float(u & 0xffff0000u);
    }
}

// ---------------- weight transform: out[tap][co][ci] (bf16) ----------------
__global__ void k_wt(const float* __restrict__ in, unsigned short* __restrict__ out,
                     int total, int CO, int CI, int sO, int sI) {
    int i = blockIdx.x * 256 + threadIdx.x;
    if (i >= total) return;
    int ci = i % CI;
    int r  = i / CI;
    int co = r % CO;
    int tp = r / CO;
    out[i] = f2b(in[(size_t)co * sO + (size_t)ci * sI + tp]);
}

// e2[k] = sum_d emb[k][d]^2
__global__ void k_e2(const float* __restrict__ emb, float* __restrict__ e2) {
    int k = blockIdx.x * 256 + threadIdx.x;
    if (k < 512) {
        const float* r = emb + k * 256;
        float s = 0.f;
        #pragma unroll 8
        for (int d = 0; d < 256; ++d) s += r[d] * r[d];
        e2[k] = s;
    }
}

// ---------------- conv1: 4x4 s2 p1, 3->256, 128->64, relu, NHWC bf16 out ----
// block 256 (1 px/thread), grid (16, 32)
__global__ __launch_bounds__(256) void k_conv1(const float* __restrict__ x,
        const float* __restrict__ w, const float* __restrict__ bias,
        unsigned short* __restrict__ out) {
    int t = threadIdx.x;
    int y = blockIdx.x * 4 + (t >> 6);
    int xq = t & 63;
    int b = blockIdx.y;
    float patch[48];
    #pragma unroll
    for (int ci = 0; ci < 3; ++ci)
        #pragma unroll
        for (int ky = 0; ky < 4; ++ky)
            #pragma unroll
            for (int kx = 0; kx < 4; ++kx) {
                int sy = 2*y - 1 + ky, sx = 2*xq - 1 + kx;
                float v = 0.f;
                if ((unsigned)sy < 128u && (unsigned)sx < 128u)
                    v = x[((b*3 + ci)*128 + sy)*128 + sx];
                patch[(ci*4 + ky)*4 + kx] = v;
            }
    unsigned short* op = out + (((size_t)(b*64 + y)*64 + xq) << 8);
    for (int c8 = 0; c8 < 32; ++c8) {
        unsigned short u8[8];
        #pragma unroll
        for (int cc = 0; cc < 8; ++cc) {
            int co = c8*8 + cc;
            float a = bias[co];                 // uniform -> scalar load
            #pragma unroll
            for (int k = 0; k < 48; ++k) a = fmaf(w[co*48 + k], patch[k], a);
            u8[cc] = f2b(fmaxf(a, 0.f));
        }
        *(uint4*)(op + c8*8) = *(uint4*)u8;
    }
}

// ---------------- unified implicit-GEMM conv (bf16 MFMA) --------------------
// MODE: 0=conv 4x4 s2 (in 64^2, out 32^2)   1=conv 3x3 p1 (relu on A)
//       2=1x1                                3=convT 4x4 s2 per-parity
// block 256 = 4 waves; tile M=64 px (2 rows of 32-grid) x N=64 co.
template<int MODE, bool RELU_OUT>
__global__ __launch_bounds__(256) void k_cgemm(
        const unsigned short* __restrict__ A,   // bf16 NHWC [B][Hin][Win][256]
        const unsigned short* __restrict__ Wt,  // bf16 [T][256co][256ci]
        const float* __restrict__ bias,
        const float* __restrict__ skipF,        // fp32 NHWC (nullable)
        unsigned short* __restrict__ outB,      // bf16 NHWC (nullable)
        float* __restrict__ outFn,              // fp32 NHWC (nullable)
        float* __restrict__ outFc) {            // fp32 NCHW 32x32 (nullable)
    constexpr int NTAPS = (MODE==0) ? 16 : (MODE==1) ? 9 : (MODE==2) ? 1 : 4;
    constexpr int HIN   = (MODE==0) ? 64 : 32;
    constexpr bool RELU_A = (MODE==1);
    constexpr bool ISCT   = (MODE==3);

    __shared__ __align__(16) unsigned short As[64*32];
    __shared__ __align__(16) unsigned short Bs[64*32];

    int t = threadIdx.x;
    int cob = blockIdx.x;            // 0..3
    int y0  = blockIdx.y * 2;        // out-row pair in 32-grid
    int bz  = blockIdx.z;
    int b   = ISCT ? (bz >> 2) : bz;
    int par = ISCT ? (bz & 3) : 0;
    int psy = par >> 1, psx = par & 1;

    // staging coords
    int spx = t >> 2, sg = t & 3;
    int soy = y0 + (spx >> 5);
    int sox = spx & 31;
    int sAoff = spx*64 + ((sg ^ ((spx >> 1) & 3)) << 4);        // bytes
    int sBco = t >> 2, sBg = t & 3;
    int sBoff = sBco*64 + ((sBg ^ ((sBco >> 1) & 3)) << 4);

    // mfma lane coords
    int wv = t >> 6, lane = t & 63;
    int mq = (wv >> 1) * 32, nq = (wv & 1) * 32;
    int lg = lane >> 4, lr = lane & 15;
    int arow0 = mq + lr,      arow1 = mq + 16 + lr;
    int aoff0 = arow0*64 + ((lg ^ ((arow0 >> 1) & 3)) << 4);
    int aoff1 = arow1*64 + ((lg ^ ((arow1 >> 1) & 3)) << 4);
    int bcol0 = nq + lr,      bcol1 = nq + 16 + lr;
    int boff0 = bcol0*64 + ((lg ^ ((bcol0 >> 1) & 3)) << 4);
    int boff1 = bcol1*64 + ((lg ^ ((bcol1 >> 1) & 3)) << 4);

    f32x4 acc[2][2];
    #pragma unroll
    for (int i = 0; i < 2; ++i)
        #pragma unroll
        for (int j = 0; j < 2; ++j) acc[i][j] = (f32x4){0.f,0.f,0.f,0.f};

    for (int tap = 0; tap < NTAPS; ++tap) {
        int tdy, tdx, wtap;
        if (MODE == 0)      { tdy = tap >> 2; tdx = tap & 3; wtap = tap; }
        else if (MODE == 1) { tdy = tap / 3;  tdx = tap % 3; wtap = tap; }
        else if (MODE == 2) { tdy = 0; tdx = 0; wtap = 0; }
        else { int jy = tap >> 1, jx = tap & 1;
               tdy = psy - jy; tdx = psx - jx;
               wtap = ((psy ? 0 : 1) + 2*jy) * 4 + ((psx ? 0 : 1) + 2*jx); }
        int sy = (MODE == 0) ? (2*soy - 1 + tdy)
               : (MODE == 1) ? (soy - 1 + tdy) : (soy + tdy);
        int sx = (MODE == 0) ? (2*sox - 1 + tdx)
               : (MODE == 1) ? (sox - 1 + tdx) : (sox + tdx);
        bool val = ((unsigned)sy < (unsigned)HIN) && ((unsigned)sx < (unsigned)HIN);
        size_t apix = val ? ((size_t)(b*HIN + sy)*HIN + sx) : 0;
        const unsigned short* ap = A + (apix << 8) + sg*8;
        const unsigned short* wp = Wt + ((size_t)wtap << 16)
                                      + (((size_t)cob*64 + sBco) << 8) + sBg*8;
        for (int kc = 0; kc < 8; ++kc) {
            __syncthreads();
            uint4 av = val ? *(const uint4*)(ap + kc*32) : (uint4){0,0,0,0};
            if (RELU_A) {
                unsigned* p = (unsigned*)&av;
                #pragma unroll
                for (int q = 0; q < 4; ++q) {
                    unsigned s = p[q] & 0x80008000u;
                    p[q] &= ~((s >> 15) * 0xFFFFu);   // zero negative bf16 halves
                }
            }
            *(uint4*)((char*)As + sAoff) = av;
            *(uint4*)((char*)Bs + sBoff) = *(const uint4*)(wp + kc*32);
            __syncthreads();
            frag_ab a0 = *(const frag_ab*)((const char*)As + aoff0);
            frag_ab a1 = *(const frag_ab*)((const char*)As + aoff1);
            frag_ab b0 = *(const frag_ab*)((const char*)Bs + boff0);
            frag_ab b1 = *(const frag_ab*)((const char*)Bs + boff1);
            acc[0][0] = __builtin_amdgcn_mfma_f32_16x16x32_bf16(a0, b0, acc[0][0], 0, 0, 0);
            acc[0][1] = __builtin_amdgcn_mfma_f32_16x16x32_bf16(a0, b1, acc[0][1], 0, 0, 0);
            acc[1][0] = __builtin_amdgcn_mfma_f32_16x16x32_bf16(a1, b0, acc[1][0], 0, 0, 0);
            acc[1][1] = __builtin_amdgcn_mfma_f32_16x16x32_bf16(a1, b1, acc[1][1], 0, 0, 0);
        }
    }

    // epilogue
    #pragma unroll
    for (int mf = 0; mf < 2; ++mf) {
        #pragma unroll
        for (int nf = 0; nf < 2; ++nf) {
            int co = cob*64 + nq + nf*16 + lr;
            float bb = bias[co];
            f32x4 v = acc[mf][nf];
            #pragma unroll
            for (int j = 0; j < 4; ++j) {
                int prow = mq + mf*16 + lg*4 + j;
                int oy = y0 + (prow >> 5);
                int ox = prow & 31;
                size_t pix;
                if (ISCT) pix = ((size_t)(b*64 + (2*oy + psy)))*64 + (2*ox + psx);
                else      pix = ((size_t)(b*32 + oy))*32 + ox;
                float xv = v[j] + bb;
                if (skipF) xv += skipF[pix*256 + co];
                if (RELU_OUT) xv = fmaxf(xv, 0.f);
                if (outB)  outB[pix*256 + co] = f2b(xv);
                if (outFn) outFn[pix*256 + co] = xv;
                if (outFc) outFc[(((size_t)b*256 + co) << 10) + oy*32 + ox] = xv;
            }
        }
    }
}

// ---------------- VQ (fp32, unchanged from round 2) -------------------------
__global__ __launch_bounds__(256) void k_vq(const float* __restrict__ ze,
        const float* __restrict__ emb, const float* __restrict__ e2,
        int* __restrict__ lat) {
    __shared__ __align__(16) float zt[256 * 36];
    __shared__ float sv[256 * 4];
    __shared__ int   si[256 * 4];
    int t = threadIdx.x;
    int y = blockIdx.x, b = blockIdx.y;
    const float* zp = ze + (b * 256) * 1024 + y * 32;
    #pragma unroll
    for (int i = 0; i < 32; ++i) {
        int l = i * 256 + t;
        zt[(l >> 5) * 36 + (l & 31)] = zp[(l >> 5) * 1024 + (l & 31)];
    }
    __syncthreads();
    int g = t & 7;
    int kg = t >> 3;
    float minv[4] = {1e30f, 1e30f, 1e30f, 1e30f};
    int   mink[4] = {0, 0, 0, 0};
    for (int pass = 0; pass < 2; ++pass) {
        float acc[4][8];
        #pragma unroll
        for (int p = 0; p < 4; ++p)
            #pragma unroll
            for (int j = 0; j < 8; ++j) acc[p][j] = 0.f;
        int k0 = pass * 256 + kg * 8;
        const float* ep = emb + k0 * 256;
        for (int d = 0; d < 256; ++d) {
            const float4 zv = *(const float4*)&zt[d * 36 + 4 * g];
            #pragma unroll
            for (int j = 0; j < 8; ++j) {
                float ev = ep[j * 256 + d];
                acc[0][j] = fmaf(ev, zv.x, acc[0][j]);
                acc[1][j] = fmaf(ev, zv.y, acc[1][j]);
                acc[2][j] = fmaf(ev, zv.z, acc[2][j]);
                acc[3][j] = fmaf(ev, zv.w, acc[3][j]);
            }
        }
        #pragma unroll
        for (int j = 0; j < 8; ++j) {
            int k = k0 + j;
            float ee = e2[k];
            #pragma unroll
            for (int p = 0; p < 4; ++p) {
                float dist = ee - 2.f * acc[p][j];
                if (dist < minv[p]) { minv[p] = dist; mink[p] = k; }
            }
        }
    }
    #pragma unroll
    for (int p = 0; p < 4; ++p) { sv[t*4+p] = minv[p]; si[t*4+p] = mink[p]; }
    __syncthreads();
    if (t < 32) {
        int gg = t >> 2, s = t & 3;
        float bv = 1e30f; int bk = 0x7fffffff;
        for (int m = 0; m < 32; ++m) {
            int tt = gg + 8 * m;
            float v = sv[tt*4+s]; int k = si[tt*4+s];
            if (v < bv || (v == bv && k < bk)) { bv = v; bk = k; }
        }
        lat[(b * 32 + y) * 32 + t] = bk;
    }
}

// gather: zq NCHW fp32 (d_out) + NHWC bf16 + NHWC fp32
__global__ __launch_bounds__(256) void k_gather(const int* __restrict__ lat,
        const float* __restrict__ emb, float* __restrict__ zqc,
        unsigned short* __restrict__ zqB, float* __restrict__ zqF) {
    __shared__ int ll[32];
    int t = threadIdx.x, y = blockIdx.x, b = blockIdx.y;
    if (t < 32) ll[t] = lat[(b * 32 + y) * 32 + t];
    __syncthreads();
    #pragma unroll
    for (int i = 0; i < 32; ++i) {
        int l = i * 256 + t;
        int d = l >> 5, xx = l & 31;
        zqc[(((size_t)b*256 + d) << 10) + y*32 + xx] = emb[ll[xx]*256 + d];
    }
    int xx = t & 31, dg = t >> 5;
    const float* e = emb + ll[xx]*256 + dg*32;
    size_t off = ((((size_t)(b*32 + y)*32 + xx)) << 8) + dg*32;
    #pragma unroll
    for (int q = 0; q < 8; ++q) {
        float4 v = *(const float4*)(e + q*4);
        *(float4*)(zqF + off + q*4) = v;
        uint2 pk;
        pk.x = (unsigned)f2b(v.x) | ((unsigned)f2b(v.y) << 16);
        pk.y = (unsigned)f2b(v.z) | ((unsigned)f2b(v.w) << 16);
        *(uint2*)(zqB + off + q*4) = pk;
    }
}

// ---------------- convT2: 4x4 s2 p1, 256->3, 64->128, sigmoid, NCHW fp32 ----
// block 256, grid (32 ytiles, 32 b); 4 out rows x 128 cols per block, 2 px/thr
__global__ __launch_bounds__(256) void k_convt2(const unsigned short* __restrict__ in,
        const unsigned short* __restrict__ Wt,  // [16][3][256] bf16
        const float* __restrict__ bias, float* __restrict__ out) {
    __shared__ __align__(16) unsigned short slab[4*66*32];  // [ri][c][ck]
    __shared__ __align__(16) unsigned short wl[16*3*32];
    int t = threadIdx.x;
    int b = blockIdx.y;
    int oy0 = blockIdx.x * 4;
    int u0 = oy0 >> 1;
    int oyl = t >> 7, ox = t & 127;
    int sy = oyl & 1, sx = ox & 1;
    int v = ox >> 1;
    float acc0[3] = {0.f,0.f,0.f}, acc1[3] = {0.f,0.f,0.f};
    for (int kc = 0; kc < 8; ++kc) {
        __syncthreads();
        for (int i = t; i < 4*66*4; i += 256) {
            int g = i & 3; int cidx = i >> 2;
            int cc = cidx % 66, ri = cidx / 66;
            int iy = u0 - 1 + ri, ix = cc - 1;
            uint4 v4 = {0,0,0,0};
            if ((unsigned)iy < 64u && (unsigned)ix < 64u)
                v4 = *(const uint4*)(in + (((size_t)(b*64 + iy)*64 + ix) << 8)
                                        + kc*32 + g*8);
            *(uint4*)(&slab[(ri*66 + cc)*32 + g*8]) = v4;
        }
        for (int i = t; i < 1536; i += 256)
            wl[i] = Wt[(i >> 5) * 256 + kc*32 + (i & 31)];
        __syncthreads();
        #pragma unroll
        for (int jy = 0; jy < 2; ++jy) {
            int duy = sy - jy;
            int riA = 1 + duy;           // u_A = u0
            #pragma unroll
            for (int jx = 0; jx < 2; ++jx) {
                int dvx = sx - jx;
                int cc = v + dvx + 1;
                int wtap = ((sy ? 0 : 1) + 2*jy)*4 + ((sx ? 0 : 1) + 2*jx);
                const unsigned short* sA = &slab[(riA*66 + cc)*32];
                const unsigned short* sB = sA + 66*32;   // riB = riA+1
                const unsigned short* wp = &wl[wtap*96];
                #pragma unroll
                for (int c8 = 0; c8 < 4; ++c8) {
                    float fA[8], fB[8], w0[8], w1[8], w2[8];
                    bf8_to_f(*(const uint4*)(sA + c8*8), fA);
                    bf8_to_f(*(const uint4*)(sB + c8*8), fB);
                    bf8_to_f(*(const uint4*)(wp + c8*8), w0);
                    bf8_to_f(*(const uint4*)(wp + 32 + c8*8), w1);
                    bf8_to_f(*(const uint4*)(wp + 64 + c8*8), w2);
                    #pragma unroll
                    for (int q = 0; q < 8; ++q) {
                        acc0[0] = fmaf(fA[q], w0[q], acc0[0]);
                        acc0[1] = fmaf(fA[q], w1[q], acc0[1]);
                        acc0[2] = fmaf(fA[q], w2[q], acc0[2]);
                        acc1[0] = fmaf(fB[q], w0[q], acc1[0]);
                        acc1[1] = fmaf(fB[q], w1[q], acc1[1]);
                        acc1[2] = fmaf(fB[q], w2[q], acc1[2]);
                    }
                }
            }
        }
    }
    #pragma unroll
    for (int co = 0; co < 3; ++co) {
        float b0 = acc0[co] + bias[co];
        float b1 = acc1[co] + bias[co];
        out[(((size_t)b*3 + co) << 14) + (oy0 + oyl)*128 + ox]     = 1.f/(1.f + __expf(-b0));
        out[(((size_t)b*3 + co) << 14) + (oy0 + oyl + 2)*128 + ox] = 1.f/(1.f + __expf(-b1));
    }
}

extern "C" void kernel_launch(void* const* d_in, const int* in_sizes, int n_in,
                              void* d_out, int out_size, void* d_ws, size_t ws_size,
                              hipStream_t stream) {
    const float* x     = (const float*)d_in[0];
    const float* ec1w  = (const float*)d_in[1];
    const float* ec1b  = (const float*)d_in[2];
    const float* ec2w  = (const float*)d_in[3];
    const float* ec2b  = (const float*)d_in[4];
    const float* er1w1 = (const float*)d_in[5];
    const float* er1b1 = (const float*)d_in[6];
    const float* er1w2 = (const float*)d_in[7];
    const float* er1b2 = (const float*)d_in[8];
    const float* er2w1 = (const float*)d_in[9];
    const float* er2b1 = (const float*)d_in[10];
    const float* er2w2 = (const float*)d_in[11];
    const float* er2b2 = (const float*)d_in[12];
    const float* emb   = (const float*)d_in[13];
    const float* dr1w1 = (const float*)d_in[14];
    const float* dr1b1 = (const float*)d_in[15];
    const float* dr1w2 = (const float*)d_in[16];
    const float* dr1b2 = (const float*)d_in[17];
    const float* dr2w1 = (const float*)d_in[18];
    const float* dr2b1 = (const float*)d_in[19];
    const float* dr2w2 = (const float*)d_in[20];
    const float* dr2b2 = (const float*)d_in[21];
    const float* dt1w  = (const float*)d_in[22];
    const float* dt1b  = (const float*)d_in[23];
    const float* dt2w  = (const float*)d_in[24];
    const float* dt2b  = (const float*)d_in[25];

    float* outp = (float*)d_out;
    float* xt = outp;                    // x_tilde 1,572,864
    float* ze = outp + 1572864;          // z_e_x   8,388,608
    float* zq = ze + 8388608;            // z_q_x   8,388,608

    char* ws = (char*)d_ws;
    unsigned short* h1B  = (unsigned short*)(ws);                 // 67,108,864 B (also convt1 out)
    unsigned short* B0   = (unsigned short*)(ws + 67108864);      // 16,777,216
    unsigned short* B1   = (unsigned short*)(ws + 83886080);      // 16,777,216
    unsigned short* T3   = (unsigned short*)(ws + 100663296);     // 16,777,216
    float*          F0   = (float*)(ws + 117440512);              // 33,554,432
    float*          F1   = (float*)(ws + 150994944);              // 33,554,432
    unsigned short* WtC2 = (unsigned short*)(ws + 184549376);     // 2,097,152
    unsigned short* Wt31 = (unsigned short*)(ws + 186646528);     // 1,179,648
    unsigned short* Wt32 = (unsigned short*)(ws + 187826176);
    unsigned short* Wt33 = (unsigned short*)(ws + 189005824);
    unsigned short* Wt34 = (unsigned short*)(ws + 190185472);
    unsigned short* W11  = (unsigned short*)(ws + 191365120);     // 131,072
    unsigned short* W12  = (unsigned short*)(ws + 191496192);
    unsigned short* W13  = (unsigned short*)(ws + 191627264);
    unsigned short* W14  = (unsigned short*)(ws + 191758336);
    unsigned short* WtT1 = (unsigned short*)(ws + 191889408);     // 2,097,152
    unsigned short* WtT2 = (unsigned short*)(ws + 193986560);     // 24,576
    float*          e2v  = (float*)(ws + 194011136);              // 2,048
    int*            lat  = (int*)(ws + 194013184);                // 131,072

    // weight transforms + e2
    k_e2<<<2, 256, 0, stream>>>(emb, e2v);
    k_wt<<<(16*65536)/256, 256, 0, stream>>>(ec2w,  WtC2, 16*65536, 256, 256, 4096, 16);
    k_wt<<<(9*65536+255)/256, 256, 0, stream>>>(er1w1, Wt31, 9*65536, 256, 256, 2304, 9);
    k_wt<<<(9*65536+255)/256, 256, 0, stream>>>(er2w1, Wt32, 9*65536, 256, 256, 2304, 9);
    k_wt<<<(9*65536+255)/256, 256, 0, stream>>>(dr1w1, Wt33, 9*65536, 256, 256, 2304, 9);
    k_wt<<<(9*65536+255)/256, 256, 0, stream>>>(dr2w1, Wt34, 9*65536, 256, 256, 2304, 9);
    k_wt<<<65536/256, 256, 0, stream>>>(er1w2, W11, 65536, 256, 256, 256, 1);
    k_wt<<<65536/256, 256, 0, stream>>>(er2w2, W12, 65536, 256, 256, 256, 1);
    k_wt<<<65536/256, 256, 0, stream>>>(dr1w2, W13, 65536, 256, 256, 256, 1);
    k_wt<<<65536/256, 256, 0, stream>>>(dr2w2, W14, 65536, 256, 256, 256, 1);
    k_wt<<<(16*65536)/256, 256, 0, stream>>>(dt1w, WtT1, 16*65536, 256, 256, 16, 4096);
    k_wt<<<(16*3*256+255)/256, 256, 0, stream>>>(dt2w, WtT2, 16*3*256, 3, 256, 16, 48);

    // encoder
    k_conv1<<<dim3(16, 32), 256, 0, stream>>>(x, ec1w, ec1b, h1B);
    k_cgemm<0,true><<<dim3(4,16,32), 256, 0, stream>>>(h1B, WtC2, ec2b,
            nullptr, B0, F0, nullptr);
    k_cgemm<1,true><<<dim3(4,16,32), 256, 0, stream>>>(B0, Wt31, er1b1,
            nullptr, T3, nullptr, nullptr);
    k_cgemm<2,false><<<dim3(4,16,32), 256, 0, stream>>>(T3, W11, er1b2,
            F0, B1, F1, nullptr);
    k_cgemm<1,true><<<dim3(4,16,32), 256, 0, stream>>>(B1, Wt32, er2b1,
            nullptr, T3, nullptr, nullptr);
    k_cgemm<2,false><<<dim3(4,16,32), 256, 0, stream>>>(T3, W12, er2b2,
            F1, nullptr, nullptr, ze);
    // VQ
    k_vq<<<dim3(32,32), 256, 0, stream>>>(ze, emb, e2v, lat);
    k_gather<<<dim3(32,32), 256, 0, stream>>>(lat, emb, zq, B0, F0);
    // decoder
    k_cgemm<1,true><<<dim3(4,16,32), 256, 0, stream>>>(B0, Wt33, dr1b1,
            nullptr, T3, nullptr, nullptr);
    k_cgemm<2,false><<<dim3(4,16,32), 256, 0, stream>>>(T3, W13, dr1b2,
            F0, B1, F1, nullptr);
    k_cgemm<1,true><<<dim3(4,16,32), 256, 0, stream>>>(B1, Wt34, dr2b1,
            nullptr, T3, nullptr, nullptr);
    k_cgemm<2,false><<<dim3(4,16,32), 256, 0, stream>>>(T3, W14, dr2b2,
            F1, B0, nullptr, nullptr);
    k_cgemm<3,true><<<dim3(4,16,128), 256, 0, stream>>>(B0, WtT1, dt1b,
            nullptr, h1B, nullptr, nullptr);
    k_convt2<<<dim3(32,32), 256, 0, stream>>>(h1B, WtT2, dt2b, xt);
}